// Round 17
// baseline (90.459 us; speedup 1.0000x reference)
//
#include <hip/hip_runtime.h>
#include <hip/hip_bf16.h>

#define SEQ   1024
#define NH    8
#define DH    64

typedef __attribute__((ext_vector_type(8))) _Float16 half8;
typedef __attribute__((ext_vector_type(4))) _Float16 half4;
typedef __attribute__((ext_vector_type(4))) float    f32x4;

#if __has_builtin(__builtin_amdgcn_exp2f)
#define EXP2F __builtin_amdgcn_exp2f
#else
#define EXP2F exp2f
#endif

__device__ inline unsigned pk2(float a, float b) {
  return __builtin_bit_cast(unsigned, __builtin_amdgcn_cvt_pkrtz(a, b));
}
__device__ inline void swap32(unsigned &a, unsigned &b) {
  asm("v_permlane32_swap_b32 %0, %1" : "+v"(a), "+v"(b));
}
__device__ inline void swap16(unsigned &a, unsigned &b) {
  asm("v_permlane16_swap_b32 %0, %1" : "+v"(a), "+v"(b));
}
__device__ inline half8 mk8(unsigned a, unsigned b, unsigned c, unsigned d) {
  union { unsigned u[4]; half8 h; } x;
  x.u[0] = a; x.u[1] = b; x.u[2] = c; x.u[3] = d;
  return x.h;
}
// async global->LDS, 16B per lane; lds base wave-uniform, HW adds lane*16
__device__ __forceinline__ void gload16(const _Float16* g, _Float16* l) {
  __builtin_amdgcn_global_load_lds((const __attribute__((address_space(1))) void*)g,
                                   (__attribute__((address_space(3))) void*)l, 16, 0, 0);
}

// counted-vmcnt barrier: drain own 4 stage loads (older), keep 2 newest (EBL dwordx4 x2) in flight
#define BARRIER2 do {                                        \
    __builtin_amdgcn_sched_barrier(0);                       \
    asm volatile("s_waitcnt vmcnt(2)" ::: "memory");         \
    __builtin_amdgcn_s_barrier();                            \
    __builtin_amdgcn_sched_barrier(0);                       \
  } while (0)

// ---------------- merged prep: cast x, weights, bias concat, dist->bin LUT ----------------
__global__ void prep_all(const float* __restrict__ x,
                         const float* __restrict__ qw, const float* __restrict__ kw,
                         const float* __restrict__ vw, const float* __restrict__ ow,
                         const float* __restrict__ qb, const float* __restrict__ kb,
                         const float* __restrict__ vb, const float* __restrict__ edges,
                         _Float16* __restrict__ xh, _Float16* __restrict__ wqkvh,
                         _Float16* __restrict__ owh, float* __restrict__ qkvbias,
                         unsigned char* __restrict__ lutd) {
  const int blk = blockIdx.x, tid = threadIdx.x;
  if (blk < 4096) {
    int g = blk * 256 + tid;
    float4 v = reinterpret_cast<const float4*>(x)[g];
    half4 u;
    u[0] = (_Float16)v.x; u[1] = (_Float16)v.y; u[2] = (_Float16)v.z; u[3] = (_Float16)v.w;
    reinterpret_cast<half4*>(xh)[g] = u;
  } else if (blk < 5122) {
    int g = (blk - 4096) * 256 + tid;
    if (g < 196608) {
      const float* src = (g < 65536) ? qw : (g < 131072) ? kw : vw;
      int lg = g & 65535;
      float4 v = reinterpret_cast<const float4*>(src)[lg];
      half4 u;
      u[0] = (_Float16)v.x; u[1] = (_Float16)v.y; u[2] = (_Float16)v.z; u[3] = (_Float16)v.w;
      reinterpret_cast<half4*>(wqkvh)[g] = u;
    } else if (g < 262144) {
      int lg = g - 196608;
      float4 v = reinterpret_cast<const float4*>(ow)[lg];
      half4 u;
      u[0] = (_Float16)v.x; u[1] = (_Float16)v.y; u[2] = (_Float16)v.z; u[3] = (_Float16)v.w;
      reinterpret_cast<half4*>(owh)[lg] = u;
    } else if (g < 262528) {
      int lg = g - 262144;
      const float* src = (lg < 128) ? qb : (lg < 256) ? kb : vb;
      int ll = lg & 127;
      reinterpret_cast<float4*>(qkvbias)[lg] = reinterpret_cast<const float4*>(src)[ll];
    }
  } else {
    int d = (blk - 5122) * 256 + tid;   // 0..5119
    float fd = (float)d;
    int bin = 0;
#pragma unroll
    for (int t = 0; t < 31; ++t) bin += (edges[t] < fd) ? 1 : 0;
    lutd[d] = (unsigned char)bin;
  }
}

// ---------------- prep: ebins, byte-permuted within each 64-k block ----------------
__global__ __launch_bounds__(256) void prep_ebins(const int* __restrict__ positions,
                                                  const float* __restrict__ mask,
                                                  const unsigned char* __restrict__ lutd,
                                                  unsigned char* __restrict__ ebins) {
  __shared__ unsigned char lutl[5120];
  __shared__ int posl[SEQ];
  __shared__ unsigned char mk[SEQ];
  const int b = blockIdx.x >> 8, j0 = (blockIdx.x & 255) * 4;
  const int tid = threadIdx.x;
  for (int i = tid; i < 1280; i += 256)
    reinterpret_cast<unsigned*>(lutl)[i] = reinterpret_cast<const unsigned*>(lutd)[i];
  for (int i = tid; i < SEQ; i += 256) {
    posl[i] = positions[b * SEQ + i];
    mk[i] = (mask[b * SEQ + i] == 0.f) ? 32 : 0;
  }
  __syncthreads();
  const int c0 = tid * 4;
  const int widx = (tid >> 4) * 16 + (tid & 3) * 4 + ((tid >> 2) & 3);
#pragma unroll
  for (int jj = 0; jj < 4; ++jj) {
    const int j = j0 + jj;
    const int pr = posl[j];
    unsigned out = 0;
#pragma unroll
    for (int r = 0; r < 4; ++r) {
      int c = c0 + r;
      int pc = posl[c];
      int d = pc - pr; d = d < 0 ? -d : d;
      if (d > 5119) d = 5119;
      unsigned e = lutl[d] | (unsigned)mk[c] | ((pc > pr) ? 64u : 0u);
      out |= e << (8 * r);
    }
    reinterpret_cast<unsigned*>(&ebins[(size_t)(b * SEQ + j) * SEQ])[widx] = out;
  }
}

// ---------------- QKV projection GEMM (128x128, BK=64, gload_lds + XOR swizzle) ----------------
// Q/K blocks (by<8): SWAPPED operands -> acc holds consecutive channels -> half4 stores.
// V blocks (by>=8): original orientation -> half4 into V^T [b][h][d][n].
__global__ __launch_bounds__(256) void qkv_gemm6(const _Float16* __restrict__ xh,
                                                 const _Float16* __restrict__ wh,
                                                 const float* __restrict__ bias,
                                                 _Float16* __restrict__ qkv) {
  __shared__ __attribute__((aligned(16))) _Float16 As[128 * 64];
  __shared__ __attribute__((aligned(16))) _Float16 Bs[128 * 64];
  const int by = blockIdx.y;
  const int m0t = blockIdx.x * 128;            // token panel
  const int tid = threadIdx.x, w = tid >> 6, lane = tid & 63;
  const int lr = lane & 15, lg = lane >> 4;
  const int wr = (w >> 1) * 64, wc = (w & 1) * 64;
  f32x4 acc[4][4] = {};
  const int srow8 = lane >> 3;
  const int scol = ((lane & 7) ^ srow8) * 8;
  const bool qk = (by < 8);
  const _Float16* Apt = qk ? (wh + (size_t)(by * 128) * 512) : (xh + (size_t)m0t * 512);
  const _Float16* Bpt = qk ? (xh + (size_t)m0t * 512)
                           : (wh + (size_t)(1024 + (by - 8) * 128) * 512);
  for (int k0 = 0; k0 < 512; k0 += 64) {
#pragma unroll
    for (int j = 0; j < 4; ++j) {
      const int row = (w * 4 + j) * 8 + srow8;
      gload16(&Apt[(size_t)row * 512 + k0 + scol], &As[(w * 4 + j) * 512]);
      gload16(&Bpt[(size_t)row * 512 + k0 + scol], &Bs[(w * 4 + j) * 512]);
    }
    __syncthreads();
#pragma unroll
    for (int kk = 0; kk < 2; ++kk) {
      half8 af[4], bf[4];
#pragma unroll
      for (int mt = 0; mt < 4; ++mt) {
        const int row = wr + mt * 16 + lr;
        af[mt] = *reinterpret_cast<const half8*>(
            (const char*)As + row * 128 + (((kk * 4 + lg) ^ (row & 7)) * 16));
      }
#pragma unroll
      for (int nt = 0; nt < 4; ++nt) {
        const int row = wc + nt * 16 + lr;
        bf[nt] = *reinterpret_cast<const half8*>(
            (const char*)Bs + row * 128 + (((kk * 4 + lg) ^ (row & 7)) * 16));
      }
#pragma unroll
      for (int mt = 0; mt < 4; ++mt)
#pragma unroll
        for (int nt = 0; nt < 4; ++nt)
          acc[mt][nt] = __builtin_amdgcn_mfma_f32_16x16x32_f16(af[mt], bf[nt], acc[mt][nt], 0, 0, 0);
    }
    __syncthreads();
  }
  if (qk) {
    const int p = by >> 2;                       // 0=Q, 1=K
    const float scl = (p == 0) ? 0.125f : 1.44269504f;
#pragma unroll
    for (int mt = 0; mt < 4; ++mt) {
      const int cb = by * 128 + wr + mt * 16 + lg * 4;      // global channel base (4 consecutive)
      const float4 bv = *reinterpret_cast<const float4*>(&bias[cb]);
      const int cp = cb & 511, h = cp >> 6, d = cp & 63;
#pragma unroll
      for (int nt = 0; nt < 4; ++nt) {
        const int t = m0t + wc + nt * 16 + lr;
        const int bb = t >> 10, nn = t & 1023;
        half4 st;
        st[0] = (_Float16)((acc[mt][nt][0] + bv.x) * scl);
        st[1] = (_Float16)((acc[mt][nt][1] + bv.y) * scl);
        st[2] = (_Float16)((acc[mt][nt][2] + bv.z) * scl);
        st[3] = (_Float16)((acc[mt][nt][3] + bv.w) * scl);
        *reinterpret_cast<half4*>(&qkv[p * 4194304 + ((bb * NH + h) * SEQ + nn) * DH + d]) = st;
      }
    }
  } else {
    const int n0 = 1024 + (by - 8) * 128;
#pragma unroll
    for (int nt = 0; nt < 4; ++nt) {
      int n = n0 + wc + nt * 16 + lr;
      float bv = bias[n];
      int c = n & 511, h = c >> 6, d = c & 63;
#pragma unroll
      for (int mt = 0; mt < 4; ++mt) {
        int m = m0t + wr + mt * 16 + lg * 4;
        int bb = m >> 10, nn = m & 1023;
        half4 st;
#pragma unroll
        for (int r = 0; r < 4; ++r) st[r] = (_Float16)(acc[mt][nt][r] + bv);
        *reinterpret_cast<half4*>(&qkv[8388608 + ((bb * NH + h) * DH + d) * SEQ + nn]) = st;
      }
    }
  }
}

// ---------------- fused attention: 4-wave blocks, 32q/wave (2 q-cols), gload_lds, no-max softmax ----------------
#define ASTAGE(bufi, kv0_) do {                                                              \
    _Pragma("unroll") for (int j = 0; j < 2; ++j) {                                          \
      const int row_ = (w * 2 + j) * 8 + (lane >> 3);                                        \
      const int c_ = ((lane & 7) ^ (row_ & 7)) * 8;                                          \
      gload16(Kg + (size_t)((kv0_) + row_) * 64 + c_, &KsL + (bufi) * 4096 + (w * 2 + j) * 512); \
      gload16(Vtg + (size_t)row_ * 1024 + (kv0_) + c_, &VtL + (bufi) * 4096 + (w * 2 + j) * 512); \
    }                                                                                        \
  } while (0)

#define EBL(dst, kt_) do {                                                                   \
    uint4 e0_ = *reinterpret_cast<const uint4*>(ebrow0 + (kt_) * 64);                        \
    uint4 e1_ = *reinterpret_cast<const uint4*>(ebrow1 + (kt_) * 64);                        \
    dst[0][0] = e0_.x; dst[0][1] = e0_.y; dst[0][2] = e0_.z; dst[0][3] = e0_.w;              \
    dst[1][0] = e1_.x; dst[1][1] = e1_.y; dst[1][2] = e1_.z; dst[1][3] = e1_.w;              \
  } while (0)

#define ACOMP(bufi, ebw) do {                                                                \
    f32x4 s[4][2];                                                                           \
    _Pragma("unroll") for (int qc = 0; qc < 2; ++qc)                                         \
      _Pragma("unroll") for (int ct = 0; ct < 4; ++ct) {                                     \
        const unsigned eb_ = ebw[qc][ct];                                                    \
        s[ct][qc][0] = elut3[eb_ & 127u];                                                    \
        s[ct][qc][1] = elut3[(eb_ >> 8) & 127u];                                             \
        s[ct][qc][2] = elut3[(eb_ >> 16) & 127u];                                            \
        s[ct][qc][3] = elut3[(eb_ >> 24) & 127u];                                            \
      }                                                                                      \
    __builtin_amdgcn_s_setprio(1);                                                           \
    _Pragma("unroll") for (int ct = 0; ct < 4; ++ct) {                                       \
      half8 kf0 = *reinterpret_cast<const half8*>(ksbase + (bufi) * 8192 + koff[ct * 2 + 0]); \
      half8 kf1 = *reinterpret_cast<const half8*>(ksbase + (bufi) * 8192 + koff[ct * 2 + 1]); \
      _Pragma("unroll") for (int qc = 0; qc < 2; ++qc) {                                     \
        s[ct][qc] = __builtin_amdgcn_mfma_f32_16x16x32_f16(kf0, qf[qc][0], s[ct][qc], 0, 0, 0); \
        s[ct][qc] = __builtin_amdgcn_mfma_f32_16x16x32_f16(kf1, qf[qc][1], s[ct][qc], 0, 0, 0); \
      }                                                                                      \
    }                                                                                        \
    __builtin_amdgcn_s_setprio(0);                                                           \
    unsigned W[2][4][2];                                                                     \
    _Pragma("unroll") for (int qc = 0; qc < 2; ++qc) {                                       \
      _Pragma("unroll") for (int ct = 0; ct < 4; ++ct) {                                     \
        float p0 = EXP2F(s[ct][qc][0]), p1 = EXP2F(s[ct][qc][1]);                            \
        float p2 = EXP2F(s[ct][qc][2]), p3 = EXP2F(s[ct][qc][3]);                            \
        l_run[qc] += (p0 + p1) + (p2 + p3);                                                  \
        W[qc][ct][0] = pk2(p0, p1);                                                          \
        W[qc][ct][1] = pk2(p2, p3);                                                          \
      }                                                                                      \
      swap32(W[qc][0][0], W[qc][1][0]); swap32(W[qc][0][1], W[qc][1][1]);                    \
      swap32(W[qc][2][0], W[qc][3][0]); swap32(W[qc][2][1], W[qc][3][1]);                    \
      swap16(W[qc][0][0], W[qc][1][0]); swap16(W[qc][0][1], W[qc][1][1]);                    \
      swap16(W[qc][2][0], W[qc][3][0]); swap16(W[qc][2][1], W[qc][3][1]);                    \
    }                                                                                        \
    __builtin_amdgcn_s_setprio(1);                                                           \
    _Pragma("unroll") for (int ks = 0; ks < 2; ++ks) {                                       \
      half8 pa0 = mk8(W[0][ks * 2][0], W[0][ks * 2][1], W[0][ks * 2 + 1][0], W[0][ks * 2 + 1][1]); \
      half8 pa1 = mk8(W[1][ks * 2][0], W[1][ks * 2][1], W[1][ks * 2 + 1][0], W[1][ks * 2 + 1][1]); \
      _Pragma("unroll") for (int dt = 0; dt < 4; ++dt) {                                     \
        half8 vf = *reinterpret_cast<const half8*>(vtbase + (bufi) * 8192 + voff[dt * 2 + ks]); \
        o[dt][0] = __builtin_amdgcn_mfma_f32_16x16x32_f16(vf, pa0, o[dt][0], 0, 0, 0);       \
        o[dt][1] = __builtin_amdgcn_mfma_f32_16x16x32_f16(vf, pa1, o[dt][1], 0, 0, 0);       \
      }                                                                                      \
    }                                                                                        \
    __builtin_amdgcn_s_setprio(0);                                                           \
  } while (0)

__global__ __launch_bounds__(256, 2) void attn14(const _Float16* __restrict__ qkv,
                                                 const float* __restrict__ mask,
                                                 const unsigned char* __restrict__ ebins,
                                                 const float* __restrict__ demb,
                                                 const float* __restrict__ obias,
                                                 _Float16* __restrict__ aout) {
  __shared__ __attribute__((aligned(16))) _Float16 Ks[2][64 * 64];
  __shared__ __attribute__((aligned(16))) _Float16 Vt[2][64 * 64];
  __shared__ float elut3[128];

  const int blk = blockIdx.x;                      // 512 blocks x 256 threads
  const int lin = (blk & 7) * 64 + (blk >> 3);     // XCD-chunked: one batch b per XCD
  const int qt = lin & 7, h = (lin >> 3) & 7, b = lin >> 6;
  const int tid = threadIdx.x, w = tid >> 6, lane = tid & 63;
  const int lr = lane & 15, lg = lane >> 4;

  const float obh = 0.5f * obias[h] * 1.44269504f;
  if (tid < 128) {
    float v;
    if (tid & 32) v = -1.442695e9f;                                  // masked
    else v = demb[(tid & 31) * NH + h] * 1.44269504f + ((tid & 64) ? obh : -obh);
    elut3[tid] = v;
  }

  const _Float16* Qg  = qkv + (size_t)(b * NH + h) * 65536;
  const _Float16* Kg  = qkv + 4194304 + (size_t)(b * NH + h) * 65536;
  const _Float16* Vtg = qkv + 8388608 + (size_t)(b * NH + h) * 65536;

  const int q_base = qt * 128 + w * 32;
  half8 qf[2][2];
#pragma unroll
  for (int qc = 0; qc < 2; ++qc)
#pragma unroll
    for (int ks = 0; ks < 2; ++ks)
      qf[qc][ks] = *reinterpret_cast<const half8*>(&Qg[(q_base + qc * 16 + lr) * DH + ks * 32 + lg * 8]);
  float mq[2];
#pragma unroll
  for (int qc = 0; qc < 2; ++qc) mq[qc] = mask[b * SEQ + q_base + qc * 16 + lr];
  const unsigned char* ebrow0 = &ebins[(size_t)(b * SEQ + q_base + lr) * SEQ + lg * 16];
  const unsigned char* ebrow1 = &ebins[(size_t)(b * SEQ + q_base + 16 + lr) * SEQ + lg * 16];

  _Float16& KsL = Ks[0][0];
  _Float16& VtL = Vt[0][0];
  const char* ksbase = (const char*)&Ks[0][0];
  const char* vtbase = (const char*)&Vt[0][0];
  int koff[8], voff[8];
#pragma unroll
  for (int ct = 0; ct < 4; ++ct) {
    const int krow = ct * 16 + lr;
    koff[ct * 2 + 0] = krow * 128 + (((0 + lg) ^ (krow & 7)) * 16);
    koff[ct * 2 + 1] = krow * 128 + (((4 + lg) ^ (krow & 7)) * 16);
    voff[ct * 2 + 0] = koff[ct * 2 + 0];
    voff[ct * 2 + 1] = koff[ct * 2 + 1];
  }

  float l_run[2] = {0.f, 0.f};
  f32x4 o[4][2] = {};

  unsigned ebwA[2][4], ebwB[2][4];
  ASTAGE(0, 0);
  EBL(ebwA, 0);
  __syncthreads();

#pragma unroll 1
  for (int i = 0; i < 8; ++i) {
    const int kt = 2 * i;
    ASTAGE(1, (kt + 1) * 64);
    EBL(ebwB, kt + 1);
    ACOMP(0, ebwA);
    BARRIER2;
    if (kt + 2 < 16) {
      ASTAGE(0, (kt + 2) * 64);
      EBL(ebwA, kt + 2);
    }
    ACOMP(1, ebwB);
    BARRIER2;
  }

  float linv[2];
#pragma unroll
  for (int qc = 0; qc < 2; ++qc) {
    float s_ = l_run[qc];
    s_ += __shfl_xor(s_, 16);
    s_ += __shfl_xor(s_, 32);
    linv[qc] = mq[qc] / fmaxf(s_, 1e-35f);
  }
#pragma unroll
  for (int dt = 0; dt < 4; ++dt)
#pragma unroll
    for (int qc = 0; qc < 2; ++qc) {
      half4 st;
#pragma unroll
      for (int r = 0; r < 4; ++r) st[r] = (_Float16)(o[dt][qc][r] * linv[qc]);
      *reinterpret_cast<half4*>(
          &aout[(size_t)(b * SEQ + q_base + qc * 16 + lr) * 512 + h * DH + dt * 16 + lg * 4]) = st;
    }
}

// ---------------- output projection GEMM (SWAPPED: 64ch x 128tok, BK=64) -> float4 stores ----------------
__global__ __launch_bounds__(256) void out_gemm6(const _Float16* __restrict__ ah,
                                                 const _Float16* __restrict__ owh,
                                                 const float* __restrict__ ob,
                                                 float* __restrict__ out) {
  __shared__ __attribute__((aligned(16))) _Float16 As[64 * 64];    // ow channel rows
  __shared__ __attribute__((aligned(16))) _Float16 Bs[128 * 64];   // token rows
  const int n0c = blockIdx.y * 64;               // channel panel (8 panels)
  const int m0t = blockIdx.x * 128;              // token panel (64 panels)
  const int tid = threadIdx.x, w = tid >> 6, lane = tid & 63;
  const int lr = lane & 15, lg = lane >> 4;
  const int wr = (w >> 1) * 32, wc = (w & 1) * 64;
  f32x4 acc[2][4] = {};
  const int srow8 = lane >> 3;
  const int scol = ((lane & 7) ^ srow8) * 8;
  for (int k0 = 0; k0 < 512; k0 += 64) {
#pragma unroll
    for (int j = 0; j < 2; ++j) {
      const int row = (w * 2 + j) * 8 + srow8;
      gload16(&owh[(size_t)(n0c + row) * 512 + k0 + scol], &As[(w * 2 + j) * 512]);
    }
#pragma unroll
    for (int j = 0; j < 4; ++j) {
      const int row = (w * 4 + j) * 8 + srow8;
      gload16(&ah[(size_t)(m0t + row) * 512 + k0 + scol], &Bs[(w * 4 + j) * 512]);
    }
    __syncthreads();
#pragma unroll
    for (int kk = 0; kk < 2; ++kk) {
      half8 af[2], bf[4];
#pragma unroll
      for (int mt = 0; mt < 2; ++mt) {
        const int row = wr + mt * 16 + lr;
        af[mt] = *reinterpret_cast<const half8*>(
            (const char*)As + row * 128 + (((kk * 4 + lg) ^ (row & 7)) * 16));
      }
#pragma unroll
      for (int nt = 0; nt < 4; ++nt) {
        const int row = wc + nt * 16 + lr;
        bf[nt] = *reinterpret_cast<const half8*>(
            (const char*)Bs + row * 128 + (((kk * 4 + lg) ^ (row & 7)) * 16));
      }
#pragma unroll
      for (int mt = 0; mt < 2; ++mt)
#pragma unroll
        for (int nt = 0; nt < 4; ++nt)
          acc[mt][nt] = __builtin_amdgcn_mfma_f32_16x16x32_f16(af[mt], bf[nt], acc[mt][nt], 0, 0, 0);
    }
    __syncthreads();
  }
#pragma unroll
  for (int mt = 0; mt < 2; ++mt) {
    const int c = n0c + wr + mt * 16 + lg * 4;       // 4 consecutive channels
    const float4 bv = *reinterpret_cast<const float4*>(&ob[c]);
#pragma unroll
    for (int nt = 0; nt < 4; ++nt) {
      const int t = m0t + wc + nt * 16 + lr;
      float4 st;
      st.x = acc[mt][nt][0] + bv.x;
      st.y = acc[mt][nt][1] + bv.y;
      st.z = acc[mt][nt][2] + bv.z;
      st.w = acc[mt][nt][3] + bv.w;
      *reinterpret_cast<float4*>(&out[(size_t)t * 512 + c]) = st;
    }
  }
}

extern "C" void kernel_launch(void* const* d_in, const int* in_sizes, int n_in,
                              void* d_out, int out_size, void* d_ws, size_t ws_size,
                              hipStream_t stream) {
  const float* x         = (const float*)d_in[0];
  const int*   positions = (const int*)d_in[1];
  const float* mask      = (const float*)d_in[2];
  const float* qw        = (const float*)d_in[3];
  const float* qb        = (const float*)d_in[4];
  const float* kw        = (const float*)d_in[5];
  const float* kb        = (const float*)d_in[6];
  const float* vw        = (const float*)d_in[7];
  const float* vb        = (const float*)d_in[8];
  const float* ow        = (const float*)d_in[9];
  const float* ob        = (const float*)d_in[10];
  const float* demb      = (const float*)d_in[11];
  const float* obias     = (const float*)d_in[12];
  const float* edges     = (const float*)d_in[13];

  char* ws = (char*)d_ws;
  _Float16* xh        = (_Float16*)(ws);                  // [0, 8M) — dead after qkv_gemm6
  unsigned char* ebins = (unsigned char*)(ws);            // reuses xh region after qkv_gemm6
  _Float16* qkv       = (_Float16*)(ws + 8388608);        // Q*0.125 | K*log2e | V^T  (24 MB)
  _Float16* aouth     = (_Float16*)(ws + 33554432);       // 8 MB
  _Float16* wqkvh     = (_Float16*)(ws + 41943040);       // 1.5 MB
  _Float16* owh       = (_Float16*)(ws + 43515904);       // 0.5 MB
  float*    qkvbias   = (float*)(ws + 44040192);          // 6 KB
  unsigned char* lutd = (unsigned char*)(ws + 44046336);  // 5120 B
  float*    outp      = (float*)d_out;

  prep_all<<<5142, 256, 0, stream>>>(x, qw, kw, vw, ow, qb, kb, vb, edges,
                                     xh, wqkvh, owh, qkvbias, lutd);
  qkv_gemm6<<<dim3(64, 12), 256, 0, stream>>>(xh, wqkvh, qkvbias, qkv);
  prep_ebins<<<2048, 256, 0, stream>>>(positions, mask, lutd, ebins);  // overwrites xh region
  attn14<<<512, 256, 0, stream>>>(qkv, mask, ebins, demb, obias, aouth);
  out_gemm6<<<dim3(64, 8), 256, 0, stream>>>(aouth, owh, ob, outp);
}

// Round 18
// 87.416 us; speedup vs baseline: 1.0348x; 1.0348x over previous
//
#include <hip/hip_runtime.h>
#include <hip/hip_bf16.h>

#define SEQ   1024
#define NH    8
#define DH    64

typedef __attribute__((ext_vector_type(8))) _Float16 half8;
typedef __attribute__((ext_vector_type(4))) _Float16 half4;
typedef __attribute__((ext_vector_type(4))) float    f32x4;

#if __has_builtin(__builtin_amdgcn_exp2f)
#define EXP2F __builtin_amdgcn_exp2f
#else
#define EXP2F exp2f
#endif

__device__ inline unsigned pk2(float a, float b) {
  return __builtin_bit_cast(unsigned, __builtin_amdgcn_cvt_pkrtz(a, b));
}
__device__ inline void swap32(unsigned &a, unsigned &b) {
  asm("v_permlane32_swap_b32 %0, %1" : "+v"(a), "+v"(b));
}
__device__ inline void swap16(unsigned &a, unsigned &b) {
  asm("v_permlane16_swap_b32 %0, %1" : "+v"(a), "+v"(b));
}
__device__ inline half8 mk8(unsigned a, unsigned b, unsigned c, unsigned d) {
  union { unsigned u[4]; half8 h; } x;
  x.u[0] = a; x.u[1] = b; x.u[2] = c; x.u[3] = d;
  return x.h;
}
// async global->LDS, 16B per lane; lds base wave-uniform, HW adds lane*16
__device__ __forceinline__ void gload16(const _Float16* g, _Float16* l) {
  __builtin_amdgcn_global_load_lds((const __attribute__((address_space(1))) void*)g,
                                   (__attribute__((address_space(3))) void*)l, 16, 0, 0);
}

// counted-vmcnt barrier: drain own 4 stage loads (older), keep 2 newest (EBL dwordx4 x2) in flight
#define BARRIER2 do {                                        \
    __builtin_amdgcn_sched_barrier(0);                       \
    asm volatile("s_waitcnt vmcnt(2)" ::: "memory");         \
    __builtin_amdgcn_s_barrier();                            \
    __builtin_amdgcn_sched_barrier(0);                       \
  } while (0)

// ---------------- merged prep: cast x, weights, bias concat, dist->bin LUT ----------------
__global__ void prep_all(const float* __restrict__ x,
                         const float* __restrict__ qw, const float* __restrict__ kw,
                         const float* __restrict__ vw, const float* __restrict__ ow,
                         const float* __restrict__ qb, const float* __restrict__ kb,
                         const float* __restrict__ vb, const float* __restrict__ edges,
                         _Float16* __restrict__ xh, _Float16* __restrict__ wqkvh,
                         _Float16* __restrict__ owh, float* __restrict__ qkvbias,
                         unsigned char* __restrict__ lutd) {
  const int blk = blockIdx.x, tid = threadIdx.x;
  if (blk < 4096) {
    int g = blk * 256 + tid;
    float4 v = reinterpret_cast<const float4*>(x)[g];
    half4 u;
    u[0] = (_Float16)v.x; u[1] = (_Float16)v.y; u[2] = (_Float16)v.z; u[3] = (_Float16)v.w;
    reinterpret_cast<half4*>(xh)[g] = u;
  } else if (blk < 5122) {
    int g = (blk - 4096) * 256 + tid;
    if (g < 196608) {
      const float* src = (g < 65536) ? qw : (g < 131072) ? kw : vw;
      int lg = g & 65535;
      float4 v = reinterpret_cast<const float4*>(src)[lg];
      half4 u;
      u[0] = (_Float16)v.x; u[1] = (_Float16)v.y; u[2] = (_Float16)v.z; u[3] = (_Float16)v.w;
      reinterpret_cast<half4*>(wqkvh)[g] = u;
    } else if (g < 262144) {
      int lg = g - 196608;
      float4 v = reinterpret_cast<const float4*>(ow)[lg];
      half4 u;
      u[0] = (_Float16)v.x; u[1] = (_Float16)v.y; u[2] = (_Float16)v.z; u[3] = (_Float16)v.w;
      reinterpret_cast<half4*>(owh)[lg] = u;
    } else if (g < 262528) {
      int lg = g - 262144;
      const float* src = (lg < 128) ? qb : (lg < 256) ? kb : vb;
      int ll = lg & 127;
      reinterpret_cast<float4*>(qkvbias)[lg] = reinterpret_cast<const float4*>(src)[ll];
    }
  } else {
    int d = (blk - 5122) * 256 + tid;   // 0..5119
    float fd = (float)d;
    int bin = 0;
#pragma unroll
    for (int t = 0; t < 31; ++t) bin += (edges[t] < fd) ? 1 : 0;
    lutd[d] = (unsigned char)bin;
  }
}

// ---------------- prep: ebins, byte-permuted within each 64-k block ----------------
// logical byte (q, k = kb*64 + ct*16 + lg*4 + r) stored at physical kb*64 + lg*16 + ct*4 + r
// so a lane (fixed lg) reads ALL 16 bytes it needs as ONE dwordx4 at kb*64 + lg*16.
__global__ __launch_bounds__(256) void prep_ebins(const int* __restrict__ positions,
                                                  const float* __restrict__ mask,
                                                  const unsigned char* __restrict__ lutd,
                                                  unsigned char* __restrict__ ebins) {
  __shared__ unsigned char lutl[5120];
  __shared__ int posl[SEQ];
  __shared__ unsigned char mk[SEQ];
  const int b = blockIdx.x >> 8, j0 = (blockIdx.x & 255) * 4;
  const int tid = threadIdx.x;
  for (int i = tid; i < 1280; i += 256)
    reinterpret_cast<unsigned*>(lutl)[i] = reinterpret_cast<const unsigned*>(lutd)[i];
  for (int i = tid; i < SEQ; i += 256) {
    posl[i] = positions[b * SEQ + i];
    mk[i] = (mask[b * SEQ + i] == 0.f) ? 32 : 0;
  }
  __syncthreads();
  const int c0 = tid * 4;
  // permuted word index: kb=tid>>4, lg=tid&3, ct=(tid>>2)&3  ->  kb*16 + lg*4 + ct
  const int widx = (tid >> 4) * 16 + (tid & 3) * 4 + ((tid >> 2) & 3);
#pragma unroll
  for (int jj = 0; jj < 4; ++jj) {
    const int j = j0 + jj;
    const int pr = posl[j];
    unsigned out = 0;
#pragma unroll
    for (int r = 0; r < 4; ++r) {
      int c = c0 + r;
      int pc = posl[c];
      int d = pc - pr; d = d < 0 ? -d : d;
      if (d > 5119) d = 5119;
      unsigned e = lutl[d] | (unsigned)mk[c] | ((pc > pr) ? 64u : 0u);
      out |= e << (8 * r);
    }
    reinterpret_cast<unsigned*>(&ebins[(size_t)(b * SEQ + j) * SEQ])[widx] = out;
  }
}

// ---------------- QKV projection GEMM (128x128, BK=64, global_load_lds + XOR swizzle) ----------------
// Q -> [b][h][n][d] * 0.125 ; K -> [b][h][n][d] * log2(e) ; V -> transposed [b][h][d][n]
__global__ __launch_bounds__(256) void qkv_gemm3(const _Float16* __restrict__ xh,
                                                 const _Float16* __restrict__ wh,
                                                 const float* __restrict__ bias,
                                                 _Float16* __restrict__ qkv) {
  __shared__ __attribute__((aligned(16))) _Float16 As[128 * 64];
  __shared__ __attribute__((aligned(16))) _Float16 Bs[128 * 64];
  const int m0 = blockIdx.x * 128, n0 = blockIdx.y * 128;
  const int tid = threadIdx.x, w = tid >> 6, lane = tid & 63;
  const int lr = lane & 15, lg = lane >> 4;
  const int wr = (w >> 1) * 64, wc = (w & 1) * 64;
  f32x4 acc[4][4] = {};
  const int srow8 = lane >> 3;                       // row offset within 8-row group
  const int scol = ((lane & 7) ^ srow8) * 8;         // pre-swizzled source chunk (halfs)
  for (int k0 = 0; k0 < 512; k0 += 64) {
#pragma unroll
    for (int j = 0; j < 4; ++j) {
      const int row = (w * 4 + j) * 8 + srow8;
      gload16(&xh[(size_t)(m0 + row) * 512 + k0 + scol], &As[(w * 4 + j) * 512]);
      gload16(&wh[(size_t)(n0 + row) * 512 + k0 + scol], &Bs[(w * 4 + j) * 512]);
    }
    __syncthreads();
#pragma unroll
    for (int kk = 0; kk < 2; ++kk) {
      half8 af[4], bf[4];
#pragma unroll
      for (int mt = 0; mt < 4; ++mt) {
        const int row = wr + mt * 16 + lr;
        af[mt] = *reinterpret_cast<const half8*>(
            (const char*)As + row * 128 + (((kk * 4 + lg) ^ (row & 7)) * 16));
      }
#pragma unroll
      for (int nt = 0; nt < 4; ++nt) {
        const int row = wc + nt * 16 + lr;
        bf[nt] = *reinterpret_cast<const half8*>(
            (const char*)Bs + row * 128 + (((kk * 4 + lg) ^ (row & 7)) * 16));
      }
#pragma unroll
      for (int mt = 0; mt < 4; ++mt)
#pragma unroll
        for (int nt = 0; nt < 4; ++nt)
          acc[mt][nt] = __builtin_amdgcn_mfma_f32_16x16x32_f16(af[mt], bf[nt], acc[mt][nt], 0, 0, 0);
    }
    __syncthreads();
  }
  const int p = n0 >> 9;   // block-uniform: 0=Q,1=K,2=V
  const float scl = (p == 0) ? 0.125f : (p == 1) ? 1.44269504f : 1.0f;
  if (p < 2) {
#pragma unroll
    for (int nt = 0; nt < 4; ++nt) {
      int n = n0 + wc + nt * 16 + lr;
      float bv = bias[n];
      int c = n & 511, h = c >> 6, d = c & 63;
#pragma unroll
      for (int mt = 0; mt < 4; ++mt)
#pragma unroll
        for (int r = 0; r < 4; ++r) {
          int m = m0 + wr + mt * 16 + lg * 4 + r;
          int bb = m >> 10, nn = m & 1023;
          qkv[p * 4194304 + ((bb * NH + h) * SEQ + nn) * DH + d] = (_Float16)((acc[mt][nt][r] + bv) * scl);
        }
    }
  } else {
#pragma unroll
    for (int nt = 0; nt < 4; ++nt) {
      int n = n0 + wc + nt * 16 + lr;
      float bv = bias[n];
      int c = n & 511, h = c >> 6, d = c & 63;
#pragma unroll
      for (int mt = 0; mt < 4; ++mt) {
        int m = m0 + wr + mt * 16 + lg * 4;
        int bb = m >> 10, nn = m & 1023;
        half4 st;
#pragma unroll
        for (int r = 0; r < 4; ++r) st[r] = (_Float16)(acc[mt][nt][r] + bv);
        *reinterpret_cast<half4*>(&qkv[8388608 + ((bb * NH + h) * DH + d) * SEQ + nn]) = st;
      }
    }
  }
}

// ---------------- fused attention: 4-wave blocks, 32q/wave (2 q-cols), gload_lds, no-max softmax ----------------
#define ASTAGE(bufi, kv0_) do {                                                              \
    _Pragma("unroll") for (int j = 0; j < 2; ++j) {                                          \
      const int row_ = (w * 2 + j) * 8 + (lane >> 3);                                        \
      const int c_ = ((lane & 7) ^ (row_ & 7)) * 8;                                          \
      gload16(Kg + (size_t)((kv0_) + row_) * 64 + c_, &KsL + (bufi) * 4096 + (w * 2 + j) * 512); \
      gload16(Vtg + (size_t)row_ * 1024 + (kv0_) + c_, &VtL + (bufi) * 4096 + (w * 2 + j) * 512); \
    }                                                                                        \
  } while (0)

// two dwordx4: all 32 ebin bytes (16 per q-col) for this lane's (lg) sub-rows of the 64-k block
#define EBL(dst, kt_) do {                                                                   \
    uint4 e0_ = *reinterpret_cast<const uint4*>(ebrow0 + (kt_) * 64);                        \
    uint4 e1_ = *reinterpret_cast<const uint4*>(ebrow1 + (kt_) * 64);                        \
    dst[0][0] = e0_.x; dst[0][1] = e0_.y; dst[0][2] = e0_.z; dst[0][3] = e0_.w;              \
    dst[1][0] = e1_.x; dst[1][1] = e1_.y; dst[1][2] = e1_.z; dst[1][3] = e1_.w;              \
  } while (0)

#define ACOMP(bufi, ebw) do {                                                                \
    f32x4 s[4][2];                                                                           \
    _Pragma("unroll") for (int qc = 0; qc < 2; ++qc)                                         \
      _Pragma("unroll") for (int ct = 0; ct < 4; ++ct) {                                     \
        const unsigned eb_ = ebw[qc][ct];                                                    \
        s[ct][qc][0] = elut3[eb_ & 127u];                                                    \
        s[ct][qc][1] = elut3[(eb_ >> 8) & 127u];                                             \
        s[ct][qc][2] = elut3[(eb_ >> 16) & 127u];                                            \
        s[ct][qc][3] = elut3[(eb_ >> 24) & 127u];                                            \
      }                                                                                      \
    __builtin_amdgcn_s_setprio(1);                                                           \
    _Pragma("unroll") for (int ct = 0; ct < 4; ++ct) {                                       \
      half8 kf0 = *reinterpret_cast<const half8*>(ksbase + (bufi) * 8192 + koff[ct * 2 + 0]); \
      half8 kf1 = *reinterpret_cast<const half8*>(ksbase + (bufi) * 8192 + koff[ct * 2 + 1]); \
      _Pragma("unroll") for (int qc = 0; qc < 2; ++qc) {                                     \
        s[ct][qc] = __builtin_amdgcn_mfma_f32_16x16x32_f16(kf0, qf[qc][0], s[ct][qc], 0, 0, 0); \
        s[ct][qc] = __builtin_amdgcn_mfma_f32_16x16x32_f16(kf1, qf[qc][1], s[ct][qc], 0, 0, 0); \
      }                                                                                      \
    }                                                                                        \
    __builtin_amdgcn_s_setprio(0);                                                           \
    /* fixed-shift softmax: P = exp2(s); scores bounded, no overflow possible */             \
    unsigned W[2][4][2];                                                                     \
    _Pragma("unroll") for (int qc = 0; qc < 2; ++qc) {                                       \
      _Pragma("unroll") for (int ct = 0; ct < 4; ++ct) {                                     \
        float p0 = EXP2F(s[ct][qc][0]), p1 = EXP2F(s[ct][qc][1]);                            \
        float p2 = EXP2F(s[ct][qc][2]), p3 = EXP2F(s[ct][qc][3]);                            \
        l_run[qc] += (p0 + p1) + (p2 + p3);                                                  \
        W[qc][ct][0] = pk2(p0, p1);                                                          \
        W[qc][ct][1] = pk2(p2, p3);                                                          \
      }                                                                                      \
      swap32(W[qc][0][0], W[qc][1][0]); swap32(W[qc][0][1], W[qc][1][1]);                    \
      swap32(W[qc][2][0], W[qc][3][0]); swap32(W[qc][2][1], W[qc][3][1]);                    \
      swap16(W[qc][0][0], W[qc][1][0]); swap16(W[qc][0][1], W[qc][1][1]);                    \
      swap16(W[qc][2][0], W[qc][3][0]); swap16(W[qc][2][1], W[qc][3][1]);                    \
    }                                                                                        \
    __builtin_amdgcn_s_setprio(1);                                                           \
    _Pragma("unroll") for (int ks = 0; ks < 2; ++ks) {                                       \
      half8 pa0 = mk8(W[0][ks * 2][0], W[0][ks * 2][1], W[0][ks * 2 + 1][0], W[0][ks * 2 + 1][1]); \
      half8 pa1 = mk8(W[1][ks * 2][0], W[1][ks * 2][1], W[1][ks * 2 + 1][0], W[1][ks * 2 + 1][1]); \
      _Pragma("unroll") for (int dt = 0; dt < 4; ++dt) {                                     \
        half8 vf = *reinterpret_cast<const half8*>(vtbase + (bufi) * 8192 + voff[dt * 2 + ks]); \
        o[dt][0] = __builtin_amdgcn_mfma_f32_16x16x32_f16(vf, pa0, o[dt][0], 0, 0, 0);       \
        o[dt][1] = __builtin_amdgcn_mfma_f32_16x16x32_f16(vf, pa1, o[dt][1], 0, 0, 0);       \
      }                                                                                      \
    }                                                                                        \
    __builtin_amdgcn_s_setprio(0);                                                           \
  } while (0)

__global__ __launch_bounds__(256, 2) void attn14(const _Float16* __restrict__ qkv,
                                                 const float* __restrict__ mask,
                                                 const unsigned char* __restrict__ ebins,
                                                 const float* __restrict__ demb,
                                                 const float* __restrict__ obias,
                                                 _Float16* __restrict__ aout) {
  __shared__ __attribute__((aligned(16))) _Float16 Ks[2][64 * 64];
  __shared__ __attribute__((aligned(16))) _Float16 Vt[2][64 * 64];
  __shared__ float elut3[128];

  const int blk = blockIdx.x;                      // 512 blocks x 256 threads
  const int lin = (blk & 7) * 64 + (blk >> 3);     // XCD-chunked: one batch b per XCD
  const int qt = lin & 7, h = (lin >> 3) & 7, b = lin >> 6;
  const int tid = threadIdx.x, w = tid >> 6, lane = tid & 63;
  const int lr = lane & 15, lg = lane >> 4;

  const float obh = 0.5f * obias[h] * 1.44269504f;
  if (tid < 128) {
    float v;
    if (tid & 32) v = -1.442695e9f;                                  // masked
    else v = demb[(tid & 31) * NH + h] * 1.44269504f + ((tid & 64) ? obh : -obh);
    elut3[tid] = v;
  }

  const _Float16* Qg  = qkv + (size_t)(b * NH + h) * 65536;
  const _Float16* Kg  = qkv + 4194304 + (size_t)(b * NH + h) * 65536;
  const _Float16* Vtg = qkv + 8388608 + (size_t)(b * NH + h) * 65536;

  const int q_base = qt * 128 + w * 32;
  half8 qf[2][2];
#pragma unroll
  for (int qc = 0; qc < 2; ++qc)
#pragma unroll
    for (int ks = 0; ks < 2; ++ks)
      qf[qc][ks] = *reinterpret_cast<const half8*>(&Qg[(q_base + qc * 16 + lr) * DH + ks * 32 + lg * 8]);
  float mq[2];
#pragma unroll
  for (int qc = 0; qc < 2; ++qc) mq[qc] = mask[b * SEQ + q_base + qc * 16 + lr];
  const unsigned char* ebrow0 = &ebins[(size_t)(b * SEQ + q_base + lr) * SEQ + lg * 16];
  const unsigned char* ebrow1 = &ebins[(size_t)(b * SEQ + q_base + 16 + lr) * SEQ + lg * 16];

  // precomputed swizzled LDS byte offsets (loop-invariant)
  _Float16& KsL = Ks[0][0];
  _Float16& VtL = Vt[0][0];
  const char* ksbase = (const char*)&Ks[0][0];
  const char* vtbase = (const char*)&Vt[0][0];
  int koff[8], voff[8];
#pragma unroll
  for (int ct = 0; ct < 4; ++ct) {
    const int krow = ct * 16 + lr;
    koff[ct * 2 + 0] = krow * 128 + (((0 + lg) ^ (krow & 7)) * 16);
    koff[ct * 2 + 1] = krow * 128 + (((4 + lg) ^ (krow & 7)) * 16);
    voff[ct * 2 + 0] = koff[ct * 2 + 0];
    voff[ct * 2 + 1] = koff[ct * 2 + 1];
  }

  float l_run[2] = {0.f, 0.f};
  f32x4 o[4][2] = {};

  unsigned ebwA[2][4], ebwB[2][4];
  ASTAGE(0, 0);
  EBL(ebwA, 0);
  __syncthreads();           // full drain once: covers elut3 init + first stage

#pragma unroll 1
  for (int i = 0; i < 8; ++i) {
    const int kt = 2 * i;
    ASTAGE(1, (kt + 1) * 64);   // stage loads first (older than EBL at barrier)
    EBL(ebwB, kt + 1);
    ACOMP(0, ebwA);
    BARRIER2;                   // drains stage-1, keeps ebwB dwordx4 pair in flight
    if (kt + 2 < 16) {
      ASTAGE(0, (kt + 2) * 64);
      EBL(ebwA, kt + 2);
    }
    ACOMP(1, ebwB);
    BARRIER2;                   // drains stage-0, keeps ebwA dwordx4 pair in flight
  }

  float linv[2];
#pragma unroll
  for (int qc = 0; qc < 2; ++qc) {
    float s_ = l_run[qc];
    s_ += __shfl_xor(s_, 16);
    s_ += __shfl_xor(s_, 32);
    linv[qc] = mq[qc] / fmaxf(s_, 1e-35f);
  }
#pragma unroll
  for (int dt = 0; dt < 4; ++dt)
#pragma unroll
    for (int qc = 0; qc < 2; ++qc) {
      half4 st;
#pragma unroll
      for (int r = 0; r < 4; ++r) st[r] = (_Float16)(o[dt][qc][r] * linv[qc]);
      *reinterpret_cast<half4*>(
          &aout[(size_t)(b * SEQ + q_base + qc * 16 + lr) * 512 + h * DH + dt * 16 + lg * 4]) = st;
    }
}

// ---------------- output projection GEMM (128x64, BK=64, global_load_lds + XOR swizzle) ----------------
__global__ __launch_bounds__(256) void out_gemm3(const _Float16* __restrict__ ah,
                                                 const _Float16* __restrict__ wh,
                                                 const float* __restrict__ ob,
                                                 float* __restrict__ out) {
  __shared__ __attribute__((aligned(16))) _Float16 As[128 * 64];
  __shared__ __attribute__((aligned(16))) _Float16 Bs[64 * 64];
  const int m0 = blockIdx.x * 128, n0 = blockIdx.y * 64;
  const int tid = threadIdx.x, w = tid >> 6, lane = tid & 63;
  const int lr = lane & 15, lg = lane >> 4;
  const int wr = (w >> 1) * 64, wc = (w & 1) * 32;
  f32x4 acc[4][2] = {};
  const int srow8 = lane >> 3;
  const int scol = ((lane & 7) ^ srow8) * 8;
  for (int k0 = 0; k0 < 512; k0 += 64) {
#pragma unroll
    for (int j = 0; j < 4; ++j) {
      const int row = (w * 4 + j) * 8 + srow8;
      gload16(&ah[(size_t)(m0 + row) * 512 + k0 + scol], &As[(w * 4 + j) * 512]);
    }
#pragma unroll
    for (int j = 0; j < 2; ++j) {
      const int row = (w * 2 + j) * 8 + srow8;
      gload16(&wh[(size_t)(n0 + row) * 512 + k0 + scol], &Bs[(w * 2 + j) * 512]);
    }
    __syncthreads();
#pragma unroll
    for (int kk = 0; kk < 2; ++kk) {
      half8 af[4], bf[2];
#pragma unroll
      for (int mt = 0; mt < 4; ++mt) {
        const int row = wr + mt * 16 + lr;
        af[mt] = *reinterpret_cast<const half8*>(
            (const char*)As + row * 128 + (((kk * 4 + lg) ^ (row & 7)) * 16));
      }
#pragma unroll
      for (int nt = 0; nt < 2; ++nt) {
        const int row = wc + nt * 16 + lr;
        bf[nt] = *reinterpret_cast<const half8*>(
            (const char*)Bs + row * 128 + (((kk * 4 + lg) ^ (row & 7)) * 16));
      }
#pragma unroll
      for (int mt = 0; mt < 4; ++mt)
#pragma unroll
        for (int nt = 0; nt < 2; ++nt)
          acc[mt][nt] = __builtin_amdgcn_mfma_f32_16x16x32_f16(af[mt], bf[nt], acc[mt][nt], 0, 0, 0);
    }
    __syncthreads();
  }
#pragma unroll
  for (int nt = 0; nt < 2; ++nt) {
    int n = n0 + wc + nt * 16 + lr;
    float bv = ob[n];
#pragma unroll
    for (int mt = 0; mt < 4; ++mt)
#pragma unroll
      for (int r = 0; r < 4; ++r) {
        int m = m0 + wr + mt * 16 + lg * 4 + r;
        out[m * 512 + n] = acc[mt][nt][r] + bv;
      }
  }
}

extern "C" void kernel_launch(void* const* d_in, const int* in_sizes, int n_in,
                              void* d_out, int out_size, void* d_ws, size_t ws_size,
                              hipStream_t stream) {
  const float* x         = (const float*)d_in[0];
  const int*   positions = (const int*)d_in[1];
  const float* mask      = (const float*)d_in[2];
  const float* qw        = (const float*)d_in[3];
  const float* qb        = (const float*)d_in[4];
  const float* kw        = (const float*)d_in[5];
  const float* kb        = (const float*)d_in[6];
  const float* vw        = (const float*)d_in[7];
  const float* vb        = (const float*)d_in[8];
  const float* ow        = (const float*)d_in[9];
  const float* ob        = (const float*)d_in[10];
  const float* demb      = (const float*)d_in[11];
  const float* obias     = (const float*)d_in[12];
  const float* edges     = (const float*)d_in[13];

  char* ws = (char*)d_ws;
  _Float16* xh        = (_Float16*)(ws);                  // [0, 8M) — dead after qkv_gemm3
  unsigned char* ebins = (unsigned char*)(ws);            // reuses xh region after qkv_gemm3
  _Float16* qkv       = (_Float16*)(ws + 8388608);        // Q*0.125 | K*log2e | V^T  (24 MB)
  _Float16* aouth     = (_Float16*)(ws + 33554432);       // 8 MB
  _Float16* wqkvh     = (_Float16*)(ws + 41943040);       // 1.5 MB
  _Float16* owh       = (_Float16*)(ws + 43515904);       // 0.5 MB
  float*    qkvbias   = (float*)(ws + 44040192);          // 6 KB
  unsigned char* lutd = (unsigned char*)(ws + 44046336);  // 5120 B
  float*    outp      = (float*)d_out;

  prep_all<<<5142, 256, 0, stream>>>(x, qw, kw, vw, ow, qb, kb, vb, edges,
                                     xh, wqkvh, owh, qkvbias, lutd);
  qkv_gemm3<<<dim3(64, 12), 256, 0, stream>>>(xh, wqkvh, qkvbias, qkv);
  prep_ebins<<<2048, 256, 0, stream>>>(positions, mask, lutd, ebins);  // overwrites xh region
  attn14<<<512, 256, 0, stream>>>(qkv, mask, ebins, demb, obias, aouth);
  out_gemm3<<<dim3(64, 8), 256, 0, stream>>>(aouth, owh, ob, outp);
}